// Round 7
// baseline (479.017 us; speedup 1.0000x reference)
//
#include <hip/hip_runtime.h>
#include <hip/hip_bf16.h>
#include <math.h>

#define NN 10000
#define NE 160000

typedef __attribute__((ext_vector_type(8))) _Float16 f16x8;
typedef __attribute__((ext_vector_type(4))) _Float16 f16x4;
typedef __attribute__((ext_vector_type(4))) float f32x4;

// ---------------- CSR build ----------------
__global__ void count_kernel(const int* __restrict__ dst, int* __restrict__ counts, int E) {
  int e = blockIdx.x * blockDim.x + threadIdx.x;
  if (e < E) atomicAdd(&counts[dst[e]], 1);
}

__global__ __launch_bounds__(1024) void scan_kernel(const int* __restrict__ counts,
                                                    int* __restrict__ row_ptr,
                                                    int* __restrict__ cursor, int N) {
  __shared__ int sums[1024];
  int t = threadIdx.x;
  const int CH = (N + 1023) >> 10;
  int base = t * CH;
  int s = 0;
  for (int i = 0; i < CH; ++i) { int idx = base + i; if (idx < N) s += counts[idx]; }
  sums[t] = s;
  __syncthreads();
  for (int off = 1; off < 1024; off <<= 1) {
    int v = 0;
    if (t >= off) v = sums[t - off];
    __syncthreads();
    if (t >= off) sums[t] += v;
    __syncthreads();
  }
  int run = (t == 0) ? 0 : sums[t - 1];
  for (int i = 0; i < CH; ++i) {
    int idx = base + i;
    if (idx < N) { row_ptr[idx] = run; cursor[idx] = run; run += counts[idx]; }
  }
  if (t == 0) row_ptr[N] = sums[1023];
}

__global__ void scatter_kernel(const int* __restrict__ src, const int* __restrict__ dst,
                               int* __restrict__ cursor, int* __restrict__ ssrc, int E) {
  int e = blockIdx.x * blockDim.x + threadIdx.x;
  if (e < E) {
    int pos = atomicAdd(&cursor[dst[e]], 1);
    ssrc[pos] = src[e];
  }
}

// ---------------- prep: all weight transposes + x conversion to fp16 ----------------
#define SEG0 (NN * 64)
#define SEG1 (1024 * 64)
#define SEG2 (1024 * 1024)
#define SEG3 (768 * 1024)
__global__ void prep_kernel(const float* __restrict__ x, const float* __restrict__ W1,
                            const float* __restrict__ W2, const float* __restrict__ W3,
                            _Float16* __restrict__ xh, _Float16* __restrict__ w1,
                            _Float16* __restrict__ w2, _Float16* __restrict__ w3) {
  int i = blockIdx.x * blockDim.x + threadIdx.x;
  if (i < SEG0) {
    int m = i >> 6, k = i & 63;
    xh[i] = (_Float16)(k < 50 ? x[m * 50 + k] : 0.f);
  } else if (i < SEG0 + SEG1) {
    int j = i - SEG0;
    int n = j >> 6, k = j & 63;
    w1[j] = (_Float16)(k < 50 ? W1[k * 1024 + n] : 0.f);
  } else if (i < SEG0 + SEG1 + SEG2) {
    int j = i - SEG0 - SEG1;
    int n = j >> 10, k = j & 1023;
    w2[j] = (_Float16)W2[k * 1024 + n];
  } else if (i < SEG0 + SEG1 + SEG2 + SEG3) {
    int j = i - SEG0 - SEG1 - SEG2;
    int n = j >> 10, k = j & 1023;
    w3[j] = (_Float16)(n < 726 ? W3[k * 726 + n] : 0.f);
  }
}

// ---------------- fp16 MFMA GEMM, XCD-swizzled, 128x128 tile, BK=64 ----------------
// PAD121: store C with head-stride 128 (gn -> (gn/121)*128 + gn%121, row stride 768)
template<int PAD121>
__global__ __launch_bounds__(256) void gemm_f16(const _Float16* __restrict__ A,
                                                const _Float16* __restrict__ B,
                                                _Float16* __restrict__ C,
                                                int M, int KP, int NcStore, int NC) {
  int flat = blockIdx.x;
  int xcd = flat & 7;
  int slot = flat >> 3;
  int cblk = slot % NC;
  int rblk = (slot / NC) * 8 + xcd;
  const int m0 = rblk * 128;
  if (m0 >= M) return;
  const int n0 = cblk * 128;

  __shared__ _Float16 As[128 * 72];
  __shared__ _Float16 Bs[128 * 72];

  const int t = threadIdx.x;
  const int lane = t & 63;
  const int wid = t >> 6;
  const int wr = wid >> 1;
  const int wc = wid & 1;
  const int row_in = lane & 15;
  const int kgrp = lane >> 4;

  f32x4 acc[4][4];
#pragma unroll
  for (int i = 0; i < 4; ++i)
#pragma unroll
    for (int j = 0; j < 4; ++j) acc[i][j] = (f32x4){0.f, 0.f, 0.f, 0.f};

  for (int k0 = 0; k0 < KP; k0 += 64) {
    if (k0) __syncthreads();
#pragma unroll
    for (int i = 0; i < 4; ++i) {
      int lin = (i * 256 + t) * 8;
      int row = lin >> 6;
      int k = lin & 63;
      int gm = m0 + row;
      if (gm >= M) gm = M - 1;
      *(f16x8*)&As[row * 72 + k] = *(const f16x8*)&A[(size_t)gm * KP + k0 + k];
      *(f16x8*)&Bs[row * 72 + k] = *(const f16x8*)&B[(size_t)(n0 + row) * KP + k0 + k];
    }
    __syncthreads();

#pragma unroll
    for (int ks = 0; ks < 64; ks += 32) {
      f16x8 a[4], b[4];
#pragma unroll
      for (int mi = 0; mi < 4; ++mi)
        a[mi] = *(const f16x8*)&As[(wr * 64 + mi * 16 + row_in) * 72 + ks + kgrp * 8];
#pragma unroll
      for (int ni = 0; ni < 4; ++ni)
        b[ni] = *(const f16x8*)&Bs[(wc * 64 + ni * 16 + row_in) * 72 + ks + kgrp * 8];
#pragma unroll
      for (int mi = 0; mi < 4; ++mi)
#pragma unroll
        for (int ni = 0; ni < 4; ++ni)
          acc[mi][ni] = __builtin_amdgcn_mfma_f32_16x16x32_f16(a[mi], b[ni], acc[mi][ni], 0, 0, 0);
    }
  }

#pragma unroll
  for (int mi = 0; mi < 4; ++mi) {
#pragma unroll
    for (int ni = 0; ni < 4; ++ni) {
      int gn = n0 + wc * 64 + ni * 16 + row_in;
      if (gn >= NcStore) continue;
#pragma unroll
      for (int j = 0; j < 4; ++j) {
        int gm = m0 + wr * 64 + mi * 16 + kgrp * 4 + j;
        if (gm >= M) continue;
        if (PAD121) {
          int h = gn / 121;
          int pc = h * 128 + (gn - h * 121);
          C[(size_t)gm * 768 + pc] = (_Float16)acc[mi][ni][j];
        } else {
          C[(size_t)gm * NcStore + gn] = (_Float16)acc[mi][ni][j];
        }
      }
    }
  }
}

// ---------------- attention scores from fp16 Wh (head stride HS, row stride SW) ----------------
template<int H, int F, int SW, int HS>
__global__ void att_kernel(const _Float16* __restrict__ Whb, const float* __restrict__ a,
                           float* __restrict__ att_s, float* __restrict__ att_d, int N) {
  int n = blockIdx.x;
  int h = threadIdx.x >> 6;
  int lane = threadIdx.x & 63;
  const _Float16* w = Whb + (size_t)n * SW + h * HS;
  const float* as = a + (size_t)h * 2 * F;
  const float* ad = as + F;
  float ss = 0.f, sd = 0.f;
  for (int f = lane; f < F; f += 64) {
    float v = (float)w[f];
    ss += v * as[f];
    sd += v * ad[f];
  }
#pragma unroll
  for (int off = 32; off > 0; off >>= 1) {
    ss += __shfl_down(ss, off);
    sd += __shfl_down(sd, off);
  }
  if (lane == 0) {
    att_s[n * H + h] = ss;
    att_d[n * H + h] = sd;
  }
}

// ---------------- fused CSR edge softmax (normalized coefs) ----------------
template<int H>
__global__ __launch_bounds__(64) void edge_softmax_csr(const int* __restrict__ row_ptr,
                                                       const int* __restrict__ ssrc,
                                                       const float* __restrict__ att_s,
                                                       const float* __restrict__ att_d,
                                                       float* __restrict__ cbuf, int N) {
  int n = blockIdx.x;
  int lane = threadIdx.x;
  int beg = row_ptr[n], end = row_ptr[n + 1];
  float ad[H];
#pragma unroll
  for (int h = 0; h < H; ++h) ad[h] = att_d[n * H + h];

  float m[H];
#pragma unroll
  for (int h = 0; h < H; ++h) m[h] = -INFINITY;
  for (int k = beg + lane; k < end; k += 64) {
    int s = ssrc[k];
#pragma unroll
    for (int h = 0; h < H; ++h) {
      float x = att_s[s * H + h] + ad[h];
      float l = x >= 0.f ? x : 0.2f * x;
      m[h] = fmaxf(m[h], l);
    }
  }
#pragma unroll
  for (int h = 0; h < H; ++h)
#pragma unroll
    for (int off = 32; off > 0; off >>= 1) m[h] = fmaxf(m[h], __shfl_xor(m[h], off));

  float sum[H];
#pragma unroll
  for (int h = 0; h < H; ++h) sum[h] = 0.f;
  for (int k = beg + lane; k < end; k += 64) {
    int s = ssrc[k];
#pragma unroll
    for (int h = 0; h < H; ++h) {
      float x = att_s[s * H + h] + ad[h];
      float l = x >= 0.f ? x : 0.2f * x;
      float ev = __expf(l - m[h]);
      cbuf[(size_t)k * H + h] = ev;
      sum[h] += ev;
    }
  }
#pragma unroll
  for (int h = 0; h < H; ++h) {
#pragma unroll
    for (int off = 32; off > 0; off >>= 1) sum[h] += __shfl_xor(sum[h], off);
    sum[h] = 1.f / (sum[h] + 1e-16f);
  }
  for (int k = beg + lane; k < end; k += 64) {
#pragma unroll
    for (int h = 0; h < H; ++h) cbuf[(size_t)k * H + h] *= sum[h];
  }
}

// ---------------- chunked aggregate for concat layers (H=4,F=256) ----------------
template<int MODE>
__global__ __launch_bounds__(256) void aggregate_cat_chunk(const int* __restrict__ row_ptr,
                                                           const int* __restrict__ ssrc,
                                                           const float* __restrict__ cbuf,
                                                           const _Float16* __restrict__ Whb,
                                                           const _Float16* __restrict__ h1,
                                                           _Float16* __restrict__ outv, int N) {
  int b = blockIdx.x;
  int chunk = b & 7;
  int group = b >> 3;
  int n = group * 16 + (threadIdx.x >> 4);
  if (n >= N) return;
  int tt = threadIdx.x & 15;
  int idx = chunk * 128 + tt * 8;
  int h = chunk >> 1;

  float acc[8] = {};
  int beg = row_ptr[n], end = row_ptr[n + 1];
  int k = beg;
  for (; k + 1 < end; k += 2) {
    int s0 = ssrc[k], s1 = ssrc[k + 1];
    float c0 = cbuf[(size_t)k * 4 + h];
    float c1 = cbuf[(size_t)(k + 1) * 4 + h];
    f16x8 w0 = *(const f16x8*)&Whb[(size_t)s0 * 1024 + idx];
    f16x8 w1 = *(const f16x8*)&Whb[(size_t)s1 * 1024 + idx];
#pragma unroll
    for (int j = 0; j < 8; ++j) {
      acc[j] += c0 * (float)w0[j];
      acc[j] += c1 * (float)w1[j];
    }
  }
  if (k < end) {
    int s0 = ssrc[k];
    float c0 = cbuf[(size_t)k * 4 + h];
    f16x8 w0 = *(const f16x8*)&Whb[(size_t)s0 * 1024 + idx];
#pragma unroll
    for (int j = 0; j < 8; ++j) acc[j] += c0 * (float)w0[j];
  }

  size_t o = (size_t)n * 1024 + idx;
  f16x8 r1;
  if (MODE == 1) r1 = *(const f16x8*)&h1[o];
  f16x8 vo;
#pragma unroll
  for (int j = 0; j < 8; ++j) {
    float v = acc[j];
    v = v > 0.f ? v : expm1f(v);
    if (MODE == 1) v += (float)r1[j];
    vo[j] = (_Float16)v;
  }
  *(f16x8*)&outv[o] = vo;
}

// ---------------- chunked aggregate for mean layer: chunk = head (6 of 8), padded SW=768 ----------------
// atomicAdd partial head-mean into out (out memset to 0 beforehand).
__global__ __launch_bounds__(256) void aggregate_mean_chunk(const int* __restrict__ row_ptr,
                                                            const int* __restrict__ ssrc,
                                                            const float* __restrict__ cbuf,
                                                            const _Float16* __restrict__ Whb,
                                                            float* __restrict__ out, int N) {
  int b = blockIdx.x;
  int h = b & 7;                 // chunk = head, pinned to XCD h
  if (h >= 6) return;
  int n = (b >> 3) * 16 + (threadIdx.x >> 4);
  if (n >= N) return;
  int tt = threadIdx.x & 15;
  int base = h * 128 + tt * 8;

  float acc[8] = {};
  int beg = row_ptr[n], end = row_ptr[n + 1];
  int k = beg;
  for (; k + 1 < end; k += 2) {
    int s0 = ssrc[k], s1 = ssrc[k + 1];
    float c0 = cbuf[(size_t)k * 6 + h];
    float c1 = cbuf[(size_t)(k + 1) * 6 + h];
    f16x8 w0 = *(const f16x8*)&Whb[(size_t)s0 * 768 + base];
    f16x8 w1 = *(const f16x8*)&Whb[(size_t)s1 * 768 + base];
#pragma unroll
    for (int j = 0; j < 8; ++j) {
      acc[j] += c0 * (float)w0[j];
      acc[j] += c1 * (float)w1[j];
    }
  }
  if (k < end) {
    int s0 = ssrc[k];
    float c0 = cbuf[(size_t)k * 6 + h];
    f16x8 w0 = *(const f16x8*)&Whb[(size_t)s0 * 768 + base];
#pragma unroll
    for (int j = 0; j < 8; ++j) acc[j] += c0 * (float)w0[j];
  }

  int f0 = tt * 8;
#pragma unroll
  for (int j = 0; j < 8; ++j) {
    int f = f0 + j;
    if (f < 121) atomicAdd(&out[(size_t)n * 121 + f], acc[j] * (1.0f / 6.0f));
  }
}

extern "C" void kernel_launch(void* const* d_in, const int* in_sizes, int n_in,
                              void* d_out, int out_size, void* d_ws, size_t ws_size,
                              hipStream_t stream) {
  const float* x  = (const float*)d_in[0];
  const int* eidx = (const int*)d_in[1];
  const float* W1 = (const float*)d_in[2];
  const float* a1 = (const float*)d_in[3];
  const float* W2 = (const float*)d_in[4];
  const float* a2 = (const float*)d_in[5];
  const float* W3 = (const float*)d_in[6];
  const float* a3 = (const float*)d_in[7];
  float* out = (float*)d_out;

  const int N = NN, E = NE;
  const int* src = eidx;
  const int* dst = eidx + E;

  char* ws = (char*)d_ws;
  size_t off = 0;
  auto alloc = [&](size_t bytes) -> void* {
    void* p = ws + off;
    off += (bytes + 255) & ~(size_t)255;
    return p;
  };
  _Float16* Whf  = (_Float16*)alloc((size_t)N * 1024 * 2);
  _Float16* h1   = (_Float16*)alloc((size_t)N * 1024 * 2);
  _Float16* hsum = (_Float16*)alloc((size_t)N * 1024 * 2);
  _Float16* xh   = (_Float16*)alloc((size_t)N * 64 * 2);
  _Float16* w1   = (_Float16*)alloc((size_t)1024 * 64 * 2);
  _Float16* w2   = (_Float16*)alloc((size_t)1024 * 1024 * 2);
  _Float16* w3   = (_Float16*)alloc((size_t)768 * 1024 * 2);
  float* cbuf  = (float*)alloc((size_t)E * 6 * 4);
  float* atts  = (float*)alloc((size_t)N * 6 * 4);
  float* attd  = (float*)alloc((size_t)N * 6 * 4);
  int* counts  = (int*)alloc((size_t)N * 4);
  int* row_ptr = (int*)alloc((size_t)(N + 1) * 4);
  int* cursor  = (int*)alloc((size_t)N * 4);
  int* ssrc    = (int*)alloc((size_t)E * 4);

  // ---- prep (weights + x) and CSR ----
  hipMemsetAsync(counts, 0, (size_t)N * 4, stream);
  prep_kernel<<<(SEG0 + SEG1 + SEG2 + SEG3 + 255) / 256, 256, 0, stream>>>(x, W1, W2, W3, xh, w1, w2, w3);
  count_kernel<<<(E + 255) / 256, 256, 0, stream>>>(dst, counts, E);
  scan_kernel<<<1, 1024, 0, stream>>>(counts, row_ptr, cursor, N);
  scatter_kernel<<<(E + 255) / 256, 256, 0, stream>>>(src, dst, cursor, ssrc, E);

  const int RPG = 10;                         // ceil(79 row-blocks / 8 XCDs)
  const int AGG_GRID = 8 * ((N + 15) / 16);   // 8 chunks x node-groups

  // ---- layer 1 ----
  gemm_f16<0><<<8 * RPG * 8, 256, 0, stream>>>(xh, w1, Whf, N, 64, 1024, 8);
  att_kernel<4, 256, 1024, 256><<<N, 256, 0, stream>>>(Whf, a1, atts, attd, N);
  edge_softmax_csr<4><<<N, 64, 0, stream>>>(row_ptr, ssrc, atts, attd, cbuf, N);
  aggregate_cat_chunk<0><<<AGG_GRID, 256, 0, stream>>>(row_ptr, ssrc, cbuf, Whf, nullptr, h1, N);

  // ---- layer 2 (aggregate emits hsum = h1 + elu(agg)) ----
  gemm_f16<0><<<8 * RPG * 8, 256, 0, stream>>>(h1, w2, Whf, N, 1024, 1024, 8);
  att_kernel<4, 256, 1024, 256><<<N, 256, 0, stream>>>(Whf, a2, atts, attd, N);
  edge_softmax_csr<4><<<N, 64, 0, stream>>>(row_ptr, ssrc, atts, attd, cbuf, N);
  aggregate_cat_chunk<1><<<AGG_GRID, 256, 0, stream>>>(row_ptr, ssrc, cbuf, Whf, h1, hsum, N);

  // ---- layer 3 (padded head-stride 128 layout; mean via atomics) ----
  gemm_f16<1><<<8 * RPG * 6, 256, 0, stream>>>(hsum, w3, Whf, N, 1024, 726, 6);
  att_kernel<6, 121, 768, 128><<<N, 384, 0, stream>>>(Whf, a3, atts, attd, N);
  edge_softmax_csr<6><<<N, 64, 0, stream>>>(row_ptr, ssrc, atts, attd, cbuf, N);
  hipMemsetAsync(out, 0, (size_t)N * 121 * 4, stream);
  aggregate_mean_chunk<<<AGG_GRID, 256, 0, stream>>>(row_ptr, ssrc, cbuf, Whf, out, N);
}

// Round 8
// 299.165 us; speedup vs baseline: 1.6012x; 1.6012x over previous
//
#include <hip/hip_runtime.h>
#include <hip/hip_bf16.h>
#include <math.h>

#define NN 10000
#define NE 160000

typedef __attribute__((ext_vector_type(8))) _Float16 f16x8;
typedef __attribute__((ext_vector_type(4))) _Float16 f16x4;
typedef __attribute__((ext_vector_type(4))) float f32x4;

// ---------------- CSR build ----------------
__global__ void count_kernel(const int* __restrict__ dst, int* __restrict__ counts, int E) {
  int e = blockIdx.x * blockDim.x + threadIdx.x;
  if (e < E) atomicAdd(&counts[dst[e]], 1);
}

__global__ __launch_bounds__(1024) void scan_kernel(const int* __restrict__ counts,
                                                    int* __restrict__ row_ptr,
                                                    int* __restrict__ cursor, int N) {
  __shared__ int sums[1024];
  int t = threadIdx.x;
  const int CH = (N + 1023) >> 10;
  int base = t * CH;
  int s = 0;
  for (int i = 0; i < CH; ++i) { int idx = base + i; if (idx < N) s += counts[idx]; }
  sums[t] = s;
  __syncthreads();
  for (int off = 1; off < 1024; off <<= 1) {
    int v = 0;
    if (t >= off) v = sums[t - off];
    __syncthreads();
    if (t >= off) sums[t] += v;
    __syncthreads();
  }
  int run = (t == 0) ? 0 : sums[t - 1];
  for (int i = 0; i < CH; ++i) {
    int idx = base + i;
    if (idx < N) { row_ptr[idx] = run; cursor[idx] = run; run += counts[idx]; }
  }
  if (t == 0) row_ptr[N] = sums[1023];
}

__global__ void scatter_kernel(const int* __restrict__ src, const int* __restrict__ dst,
                               int* __restrict__ cursor, int* __restrict__ ssrc, int E) {
  int e = blockIdx.x * blockDim.x + threadIdx.x;
  if (e < E) {
    int pos = atomicAdd(&cursor[dst[e]], 1);
    ssrc[pos] = src[e];
  }
}

// ---------------- prep: all weight transposes + x conversion to fp16 ----------------
#define SEG0 (NN * 64)
#define SEG1 (1024 * 64)
#define SEG2 (1024 * 1024)
#define SEG3 (768 * 1024)
__global__ void prep_kernel(const float* __restrict__ x, const float* __restrict__ W1,
                            const float* __restrict__ W2, const float* __restrict__ W3,
                            _Float16* __restrict__ xh, _Float16* __restrict__ w1,
                            _Float16* __restrict__ w2, _Float16* __restrict__ w3) {
  int i = blockIdx.x * blockDim.x + threadIdx.x;
  if (i < SEG0) {
    int m = i >> 6, k = i & 63;
    xh[i] = (_Float16)(k < 50 ? x[m * 50 + k] : 0.f);
  } else if (i < SEG0 + SEG1) {
    int j = i - SEG0;
    int n = j >> 6, k = j & 63;
    w1[j] = (_Float16)(k < 50 ? W1[k * 1024 + n] : 0.f);
  } else if (i < SEG0 + SEG1 + SEG2) {
    int j = i - SEG0 - SEG1;
    int n = j >> 10, k = j & 1023;
    w2[j] = (_Float16)W2[k * 1024 + n];
  } else if (i < SEG0 + SEG1 + SEG2 + SEG3) {
    int j = i - SEG0 - SEG1 - SEG2;
    int n = j >> 10, k = j & 1023;
    w3[j] = (_Float16)(n < 726 ? W3[k * 726 + n] : 0.f);
  }
}

// ---------------- fp16 MFMA GEMM, XCD-swizzled, 128x128 tile, BK=64 ----------------
// PAD121: store C with head-stride 128 (gn -> (gn/121)*128 + gn%121, row stride 768)
template<int PAD121>
__global__ __launch_bounds__(256) void gemm_f16(const _Float16* __restrict__ A,
                                                const _Float16* __restrict__ B,
                                                _Float16* __restrict__ C,
                                                int M, int KP, int NcStore, int NC) {
  int flat = blockIdx.x;
  int xcd = flat & 7;
  int slot = flat >> 3;
  int cblk = slot % NC;
  int rblk = (slot / NC) * 8 + xcd;
  const int m0 = rblk * 128;
  if (m0 >= M) return;
  const int n0 = cblk * 128;

  __shared__ _Float16 As[128 * 72];
  __shared__ _Float16 Bs[128 * 72];

  const int t = threadIdx.x;
  const int lane = t & 63;
  const int wid = t >> 6;
  const int wr = wid >> 1;
  const int wc = wid & 1;
  const int row_in = lane & 15;
  const int kgrp = lane >> 4;

  f32x4 acc[4][4];
#pragma unroll
  for (int i = 0; i < 4; ++i)
#pragma unroll
    for (int j = 0; j < 4; ++j) acc[i][j] = (f32x4){0.f, 0.f, 0.f, 0.f};

  for (int k0 = 0; k0 < KP; k0 += 64) {
    if (k0) __syncthreads();
#pragma unroll
    for (int i = 0; i < 4; ++i) {
      int lin = (i * 256 + t) * 8;
      int row = lin >> 6;
      int k = lin & 63;
      int gm = m0 + row;
      if (gm >= M) gm = M - 1;
      *(f16x8*)&As[row * 72 + k] = *(const f16x8*)&A[(size_t)gm * KP + k0 + k];
      *(f16x8*)&Bs[row * 72 + k] = *(const f16x8*)&B[(size_t)(n0 + row) * KP + k0 + k];
    }
    __syncthreads();

#pragma unroll
    for (int ks = 0; ks < 64; ks += 32) {
      f16x8 a[4], b[4];
#pragma unroll
      for (int mi = 0; mi < 4; ++mi)
        a[mi] = *(const f16x8*)&As[(wr * 64 + mi * 16 + row_in) * 72 + ks + kgrp * 8];
#pragma unroll
      for (int ni = 0; ni < 4; ++ni)
        b[ni] = *(const f16x8*)&Bs[(wc * 64 + ni * 16 + row_in) * 72 + ks + kgrp * 8];
#pragma unroll
      for (int mi = 0; mi < 4; ++mi)
#pragma unroll
        for (int ni = 0; ni < 4; ++ni)
          acc[mi][ni] = __builtin_amdgcn_mfma_f32_16x16x32_f16(a[mi], b[ni], acc[mi][ni], 0, 0, 0);
    }
  }

#pragma unroll
  for (int mi = 0; mi < 4; ++mi) {
#pragma unroll
    for (int ni = 0; ni < 4; ++ni) {
      int gn = n0 + wc * 64 + ni * 16 + row_in;
      if (gn >= NcStore) continue;
#pragma unroll
      for (int j = 0; j < 4; ++j) {
        int gm = m0 + wr * 64 + mi * 16 + kgrp * 4 + j;
        if (gm >= M) continue;
        if (PAD121) {
          int h = gn / 121;
          int pc = h * 128 + (gn - h * 121);
          C[(size_t)gm * 768 + pc] = (_Float16)acc[mi][ni][j];
        } else {
          C[(size_t)gm * NcStore + gn] = (_Float16)acc[mi][ni][j];
        }
      }
    }
  }
}

// ---------------- attention scores from fp16 Wh (head stride HS, row stride SW) ----------------
template<int H, int F, int SW, int HS>
__global__ void att_kernel(const _Float16* __restrict__ Whb, const float* __restrict__ a,
                           float* __restrict__ att_s, float* __restrict__ att_d, int N) {
  int n = blockIdx.x;
  int h = threadIdx.x >> 6;
  int lane = threadIdx.x & 63;
  const _Float16* w = Whb + (size_t)n * SW + h * HS;
  const float* as = a + (size_t)h * 2 * F;
  const float* ad = as + F;
  float ss = 0.f, sd = 0.f;
  for (int f = lane; f < F; f += 64) {
    float v = (float)w[f];
    ss += v * as[f];
    sd += v * ad[f];
  }
#pragma unroll
  for (int off = 32; off > 0; off >>= 1) {
    ss += __shfl_down(ss, off);
    sd += __shfl_down(sd, off);
  }
  if (lane == 0) {
    att_s[n * H + h] = ss;
    att_d[n * H + h] = sd;
  }
}

// ---------------- fused CSR edge softmax (normalized coefs) ----------------
template<int H>
__global__ __launch_bounds__(64) void edge_softmax_csr(const int* __restrict__ row_ptr,
                                                       const int* __restrict__ ssrc,
                                                       const float* __restrict__ att_s,
                                                       const float* __restrict__ att_d,
                                                       float* __restrict__ cbuf, int N) {
  int n = blockIdx.x;
  int lane = threadIdx.x;
  int beg = row_ptr[n], end = row_ptr[n + 1];
  float ad[H];
#pragma unroll
  for (int h = 0; h < H; ++h) ad[h] = att_d[n * H + h];

  float m[H];
#pragma unroll
  for (int h = 0; h < H; ++h) m[h] = -INFINITY;
  for (int k = beg + lane; k < end; k += 64) {
    int s = ssrc[k];
#pragma unroll
    for (int h = 0; h < H; ++h) {
      float x = att_s[s * H + h] + ad[h];
      float l = x >= 0.f ? x : 0.2f * x;
      m[h] = fmaxf(m[h], l);
    }
  }
#pragma unroll
  for (int h = 0; h < H; ++h)
#pragma unroll
    for (int off = 32; off > 0; off >>= 1) m[h] = fmaxf(m[h], __shfl_xor(m[h], off));

  float sum[H];
#pragma unroll
  for (int h = 0; h < H; ++h) sum[h] = 0.f;
  for (int k = beg + lane; k < end; k += 64) {
    int s = ssrc[k];
#pragma unroll
    for (int h = 0; h < H; ++h) {
      float x = att_s[s * H + h] + ad[h];
      float l = x >= 0.f ? x : 0.2f * x;
      float ev = __expf(l - m[h]);
      cbuf[(size_t)k * H + h] = ev;
      sum[h] += ev;
    }
  }
#pragma unroll
  for (int h = 0; h < H; ++h) {
#pragma unroll
    for (int off = 32; off > 0; off >>= 1) sum[h] += __shfl_xor(sum[h], off);
    sum[h] = 1.f / (sum[h] + 1e-16f);
  }
  for (int k = beg + lane; k < end; k += 64) {
#pragma unroll
    for (int h = 0; h < H; ++h) cbuf[(size_t)k * H + h] *= sum[h];
  }
}

// ---------------- chunked aggregate for concat layers (H=4,F=256) ----------------
template<int MODE>
__global__ __launch_bounds__(256) void aggregate_cat_chunk(const int* __restrict__ row_ptr,
                                                           const int* __restrict__ ssrc,
                                                           const float* __restrict__ cbuf,
                                                           const _Float16* __restrict__ Whb,
                                                           const _Float16* __restrict__ h1,
                                                           _Float16* __restrict__ outv, int N) {
  int b = blockIdx.x;
  int chunk = b & 7;
  int group = b >> 3;
  int n = group * 16 + (threadIdx.x >> 4);
  if (n >= N) return;
  int tt = threadIdx.x & 15;
  int idx = chunk * 128 + tt * 8;
  int h = chunk >> 1;

  float acc[8] = {};
  int beg = row_ptr[n], end = row_ptr[n + 1];
  int k = beg;
  for (; k + 1 < end; k += 2) {
    int s0 = ssrc[k], s1 = ssrc[k + 1];
    float c0 = cbuf[(size_t)k * 4 + h];
    float c1 = cbuf[(size_t)(k + 1) * 4 + h];
    f16x8 w0 = *(const f16x8*)&Whb[(size_t)s0 * 1024 + idx];
    f16x8 w1 = *(const f16x8*)&Whb[(size_t)s1 * 1024 + idx];
#pragma unroll
    for (int j = 0; j < 8; ++j) {
      acc[j] += c0 * (float)w0[j];
      acc[j] += c1 * (float)w1[j];
    }
  }
  if (k < end) {
    int s0 = ssrc[k];
    float c0 = cbuf[(size_t)k * 4 + h];
    f16x8 w0 = *(const f16x8*)&Whb[(size_t)s0 * 1024 + idx];
#pragma unroll
    for (int j = 0; j < 8; ++j) acc[j] += c0 * (float)w0[j];
  }

  size_t o = (size_t)n * 1024 + idx;
  f16x8 r1;
  if (MODE == 1) r1 = *(const f16x8*)&h1[o];
  f16x8 vo;
#pragma unroll
  for (int j = 0; j < 8; ++j) {
    float v = acc[j];
    v = v > 0.f ? v : expm1f(v);
    if (MODE == 1) v += (float)r1[j];
    vo[j] = (_Float16)v;
  }
  *(f16x8*)&outv[o] = vo;
}

// ---------------- chunked aggregate for mean layer: chunk = head (6 of 8), padded SW=768 ----------------
// writes NON-ATOMIC partial head-slices into part[n][h*128+f] (fp32).
__global__ __launch_bounds__(256) void aggregate_mean_chunk(const int* __restrict__ row_ptr,
                                                            const int* __restrict__ ssrc,
                                                            const float* __restrict__ cbuf,
                                                            const _Float16* __restrict__ Whb,
                                                            float* __restrict__ part, int N) {
  int b = blockIdx.x;
  int h = b & 7;                 // chunk = head, pinned to XCD h
  if (h >= 6) return;
  int n = (b >> 3) * 16 + (threadIdx.x >> 4);
  if (n >= N) return;
  int tt = threadIdx.x & 15;
  int base = h * 128 + tt * 8;

  float acc[8] = {};
  int beg = row_ptr[n], end = row_ptr[n + 1];
  int k = beg;
  for (; k + 1 < end; k += 2) {
    int s0 = ssrc[k], s1 = ssrc[k + 1];
    float c0 = cbuf[(size_t)k * 6 + h];
    float c1 = cbuf[(size_t)(k + 1) * 6 + h];
    f16x8 w0 = *(const f16x8*)&Whb[(size_t)s0 * 768 + base];
    f16x8 w1 = *(const f16x8*)&Whb[(size_t)s1 * 768 + base];
#pragma unroll
    for (int j = 0; j < 8; ++j) {
      acc[j] += c0 * (float)w0[j];
      acc[j] += c1 * (float)w1[j];
    }
  }
  if (k < end) {
    int s0 = ssrc[k];
    float c0 = cbuf[(size_t)k * 6 + h];
    f16x8 w0 = *(const f16x8*)&Whb[(size_t)s0 * 768 + base];
#pragma unroll
    for (int j = 0; j < 8; ++j) acc[j] += c0 * (float)w0[j];
  }

  float* p = &part[(size_t)n * 768 + base];
  *(f32x4*)&p[0] = (f32x4){acc[0], acc[1], acc[2], acc[3]};
  *(f32x4*)&p[4] = (f32x4){acc[4], acc[5], acc[6], acc[7]};
}

// ---------------- reduce 6 head-slices -> out[n][121] ----------------
__global__ __launch_bounds__(128) void reduce_mean(const float* __restrict__ part,
                                                   float* __restrict__ out, int N) {
  int n = blockIdx.x;
  int f = threadIdx.x;
  if (f >= 121) return;
  const float* p = &part[(size_t)n * 768];
  float s = 0.f;
#pragma unroll
  for (int h = 0; h < 6; ++h) s += p[h * 128 + f];
  out[(size_t)n * 121 + f] = s * (1.0f / 6.0f);
}

extern "C" void kernel_launch(void* const* d_in, const int* in_sizes, int n_in,
                              void* d_out, int out_size, void* d_ws, size_t ws_size,
                              hipStream_t stream) {
  const float* x  = (const float*)d_in[0];
  const int* eidx = (const int*)d_in[1];
  const float* W1 = (const float*)d_in[2];
  const float* a1 = (const float*)d_in[3];
  const float* W2 = (const float*)d_in[4];
  const float* a2 = (const float*)d_in[5];
  const float* W3 = (const float*)d_in[6];
  const float* a3 = (const float*)d_in[7];
  float* out = (float*)d_out;

  const int N = NN, E = NE;
  const int* src = eidx;
  const int* dst = eidx + E;

  char* ws = (char*)d_ws;
  size_t off = 0;
  auto alloc = [&](size_t bytes) -> void* {
    void* p = ws + off;
    off += (bytes + 255) & ~(size_t)255;
    return p;
  };
  _Float16* Whf  = (_Float16*)alloc((size_t)N * 1024 * 2);
  _Float16* h1   = (_Float16*)alloc((size_t)N * 1024 * 2);
  _Float16* hsum = (_Float16*)alloc((size_t)N * 1024 * 2);
  _Float16* xh   = (_Float16*)alloc((size_t)N * 64 * 2);
  _Float16* w1   = (_Float16*)alloc((size_t)1024 * 64 * 2);
  _Float16* w2   = (_Float16*)alloc((size_t)1024 * 1024 * 2);
  _Float16* w3   = (_Float16*)alloc((size_t)768 * 1024 * 2);
  float* cbuf  = (float*)alloc((size_t)E * 6 * 4);
  float* part  = (float*)alloc((size_t)N * 768 * 4);   // mean-layer partials
  float* atts  = (float*)alloc((size_t)N * 6 * 4);
  float* attd  = (float*)alloc((size_t)N * 6 * 4);
  int* counts  = (int*)alloc((size_t)N * 4);
  int* row_ptr = (int*)alloc((size_t)(N + 1) * 4);
  int* cursor  = (int*)alloc((size_t)N * 4);
  int* ssrc    = (int*)alloc((size_t)E * 4);

  // ---- prep (weights + x) and CSR ----
  hipMemsetAsync(counts, 0, (size_t)N * 4, stream);
  prep_kernel<<<(SEG0 + SEG1 + SEG2 + SEG3 + 255) / 256, 256, 0, stream>>>(x, W1, W2, W3, xh, w1, w2, w3);
  count_kernel<<<(E + 255) / 256, 256, 0, stream>>>(dst, counts, E);
  scan_kernel<<<1, 1024, 0, stream>>>(counts, row_ptr, cursor, N);
  scatter_kernel<<<(E + 255) / 256, 256, 0, stream>>>(src, dst, cursor, ssrc, E);

  const int RPG = 10;                         // ceil(79 row-blocks / 8 XCDs)
  const int AGG_GRID = 8 * ((N + 15) / 16);   // 8 chunks x node-groups

  // ---- layer 1 ----
  gemm_f16<0><<<8 * RPG * 8, 256, 0, stream>>>(xh, w1, Whf, N, 64, 1024, 8);
  att_kernel<4, 256, 1024, 256><<<N, 256, 0, stream>>>(Whf, a1, atts, attd, N);
  edge_softmax_csr<4><<<N, 64, 0, stream>>>(row_ptr, ssrc, atts, attd, cbuf, N);
  aggregate_cat_chunk<0><<<AGG_GRID, 256, 0, stream>>>(row_ptr, ssrc, cbuf, Whf, nullptr, h1, N);

  // ---- layer 2 (aggregate emits hsum = h1 + elu(agg)) ----
  gemm_f16<0><<<8 * RPG * 8, 256, 0, stream>>>(h1, w2, Whf, N, 1024, 1024, 8);
  att_kernel<4, 256, 1024, 256><<<N, 256, 0, stream>>>(Whf, a2, atts, attd, N);
  edge_softmax_csr<4><<<N, 64, 0, stream>>>(row_ptr, ssrc, atts, attd, cbuf, N);
  aggregate_cat_chunk<1><<<AGG_GRID, 256, 0, stream>>>(row_ptr, ssrc, cbuf, Whf, h1, hsum, N);

  // ---- layer 3 (padded head-stride 128 layout; partials + reduce) ----
  gemm_f16<1><<<8 * RPG * 6, 256, 0, stream>>>(hsum, w3, Whf, N, 1024, 726, 6);
  att_kernel<6, 121, 768, 128><<<N, 384, 0, stream>>>(Whf, a3, atts, attd, N);
  edge_softmax_csr<6><<<N, 64, 0, stream>>>(row_ptr, ssrc, atts, attd, cbuf, N);
  aggregate_mean_chunk<<<AGG_GRID, 256, 0, stream>>>(row_ptr, ssrc, cbuf, Whf, part, N);
  reduce_mean<<<N, 128, 0, stream>>>(part, out, N);
}